// Round 1
// baseline (4031.310 us; speedup 1.0000x reference)
//
#include <hip/hip_runtime.h>
#include <math.h>

#define BB 2
#define SS 2048
#define HH 16
#define DD 64
#define DMODEL 1024
#define MROWS (BB * SS)   // 4096

// ---------------------------------------------------------------------------
// GEMM: C[m,n] = sum_k A[m,k] * W[n,k] + bias[n]
//   A: M x K (or gathered from (B,H,S,D) layout if gather_heads)
//   W: N x K row-major (nn.Linear weight)
//   out: split_heads ? (B,H,S,D) : M x N row-major
// Tiling: 64x64 block tile, BK=16, 256 threads, 4x4 microtile per thread.
// ---------------------------------------------------------------------------
__global__ __launch_bounds__(256) void gemm_bias(const float* __restrict__ A,
                                                 const float* __restrict__ W,
                                                 const float* __restrict__ bias,
                                                 float* __restrict__ out,
                                                 int split_heads, int gather_heads)
{
    __shared__ float As[16][65];
    __shared__ float Ws[16][65];

    const int tid  = threadIdx.x;
    const int tx   = tid & 15;     // 0..15
    const int ty   = tid >> 4;     // 0..15
    const int row0 = blockIdx.x * 64;
    const int col0 = blockIdx.y * 64;

    // loader mapping: thread -> (row-in-tile, k-quad)
    const int lmm = tid >> 2;        // 0..63
    const int lkq = (tid & 3) * 4;   // 0,4,8,12

    float acc[4][4] = {};

    for (int k0 = 0; k0 < DMODEL; k0 += 16) {
        // ---- load A tile (64 x 16) ----
        float4 av4;
        if (!gather_heads) {
            av4 = *reinterpret_cast<const float4*>(&A[(row0 + lmm) * DMODEL + k0 + lkq]);
        } else {
            // A[m,k] = av[((b*H + h)*S + s)*D + d], m=b*S+s, k=h*D+d
            const int m = row0 + lmm;
            const int b = m >> 11, s = m & 2047;
            const int k = k0 + lkq;
            const int h = k >> 6, d = k & 63;
            av4 = *reinterpret_cast<const float4*>(&A[(((b * HH + h) * SS) + s) * DD + d]);
        }
        As[lkq + 0][lmm] = av4.x;
        As[lkq + 1][lmm] = av4.y;
        As[lkq + 2][lmm] = av4.z;
        As[lkq + 3][lmm] = av4.w;

        // ---- load W tile (64 x 16) ----
        float4 wv4 = *reinterpret_cast<const float4*>(&W[(col0 + lmm) * DMODEL + k0 + lkq]);
        Ws[lkq + 0][lmm] = wv4.x;
        Ws[lkq + 1][lmm] = wv4.y;
        Ws[lkq + 2][lmm] = wv4.z;
        Ws[lkq + 3][lmm] = wv4.w;

        __syncthreads();

        #pragma unroll
        for (int kk = 0; kk < 16; ++kk) {
            float a[4], w[4];
            #pragma unroll
            for (int i = 0; i < 4; ++i) a[i] = As[kk][ty + 16 * i];
            #pragma unroll
            for (int j = 0; j < 4; ++j) w[j] = Ws[kk][tx + 16 * j];
            #pragma unroll
            for (int i = 0; i < 4; ++i)
                #pragma unroll
                for (int j = 0; j < 4; ++j)
                    acc[i][j] += a[i] * w[j];
        }
        __syncthreads();
    }

    #pragma unroll
    for (int i = 0; i < 4; ++i) {
        const int m = row0 + ty + 16 * i;
        #pragma unroll
        for (int j = 0; j < 4; ++j) {
            const int n = col0 + tx + 16 * j;
            const float val = acc[i][j] + bias[n];
            if (!split_heads) {
                out[m * DMODEL + n] = val;
            } else {
                const int b = m >> 11, s = m & 2047;
                const int h = n >> 6, d = n & 63;
                out[(((b * HH + h) * SS) + s) * DD + d] = val;
            }
        }
    }
}

// ---------------------------------------------------------------------------
// Causal attention, online softmax. One 64-thread wave per 64-query tile.
// q,k,v,av all in (B,H,S,D). Each thread owns one query row.
// gridDim = (16, H, B); each block does q-tiles {x, 31-x} -> uniform 33 k-tiles.
// ---------------------------------------------------------------------------
__global__ __launch_bounds__(64) void attn_causal(const float* __restrict__ q,
                                                  const float* __restrict__ k,
                                                  const float* __restrict__ v,
                                                  float* __restrict__ av)
{
    __shared__ float Ks[64][68];   // pad to 68 -> 16B-aligned rows, conflict-light
    __shared__ float Vs[64][68];

    const int t = threadIdx.x;
    const int h = blockIdx.y, b = blockIdx.z;
    const int base = (b * HH + h) * SS * DD;

    for (int pass = 0; pass < 2; ++pass) {
        const int qt   = pass ? (31 - (int)blockIdx.x) : (int)blockIdx.x;
        const int q0   = qt * 64;
        const int qrow = q0 + t;

        __syncthreads();   // protect LDS from previous pass's readers

        // stage Q tile coalesced, then copy own row to registers
        for (int r = 0; r < 64; ++r)
            Ks[r][t] = q[base + (q0 + r) * DD + t];
        __syncthreads();

        float qv[DD];
        {
            const float4* Qr = reinterpret_cast<const float4*>(&Ks[t][0]);
            #pragma unroll
            for (int d4 = 0; d4 < 16; ++d4) {
                float4 x = Qr[d4];
                qv[4 * d4 + 0] = x.x; qv[4 * d4 + 1] = x.y;
                qv[4 * d4 + 2] = x.z; qv[4 * d4 + 3] = x.w;
            }
        }

        float mrun = -1e30f, lrun = 0.0f;
        float O[DD];
        #pragma unroll
        for (int d = 0; d < DD; ++d) O[d] = 0.0f;

        for (int kt = 0; kt <= qt; ++kt) {
            const int k0 = kt * 64;
            __syncthreads();   // previous tile fully consumed (also covers qv copy)
            for (int r = 0; r < 64; ++r) {
                Ks[r][t] = k[base + (k0 + r) * DD + t];
                Vs[r][t] = v[base + (k0 + r) * DD + t];
            }
            __syncthreads();

            const int jmax = qrow - k0;   // j <= jmax is unmasked; j=0 always valid
            for (int j = 0; j < 64; ++j) {
                const float4* Kr = reinterpret_cast<const float4*>(&Ks[j][0]);
                float s0 = 0.f, s1 = 0.f, s2 = 0.f, s3 = 0.f;
                #pragma unroll
                for (int d4 = 0; d4 < 16; ++d4) {
                    float4 kk4 = Kr[d4];
                    s0 += qv[4 * d4 + 0] * kk4.x;
                    s1 += qv[4 * d4 + 1] * kk4.y;
                    s2 += qv[4 * d4 + 2] * kk4.z;
                    s3 += qv[4 * d4 + 3] * kk4.w;
                }
                float s = ((s0 + s1) + (s2 + s3)) * 0.125f;
                if (j > jmax) s = -1e30f;   // masked -> p underflows to exactly 0

                const float mnew  = fmaxf(mrun, s);
                const float alpha = __expf(mrun - mnew);
                const float p     = __expf(s - mnew);
                lrun = lrun * alpha + p;

                const float4* Vr = reinterpret_cast<const float4*>(&Vs[j][0]);
                #pragma unroll
                for (int d4 = 0; d4 < 16; ++d4) {
                    float4 vv4 = Vr[d4];
                    O[4 * d4 + 0] = O[4 * d4 + 0] * alpha + p * vv4.x;
                    O[4 * d4 + 1] = O[4 * d4 + 1] * alpha + p * vv4.y;
                    O[4 * d4 + 2] = O[4 * d4 + 2] * alpha + p * vv4.z;
                    O[4 * d4 + 3] = O[4 * d4 + 3] * alpha + p * vv4.w;
                }
                mrun = mnew;
            }
        }

        // write back: stage rows in LDS so the global store is coalesced
        const float inv = 1.0f / lrun;
        __syncthreads();
        #pragma unroll
        for (int d = 0; d < DD; ++d) Ks[t][d] = O[d] * inv;
        __syncthreads();
        for (int r = 0; r < 64; ++r)
            av[base + (q0 + r) * DD + t] = Ks[r][t];
    }
}

extern "C" void kernel_launch(void* const* d_in, const int* in_sizes, int n_in,
                              void* d_out, int out_size, void* d_ws, size_t ws_size,
                              hipStream_t stream) {
    const float* queries = (const float*)d_in[0];
    const float* keys    = (const float*)d_in[1];
    const float* values  = (const float*)d_in[2];
    // d_in[3] = mask: exactly tril(ones) broadcast -> hardcoded causal, not read
    const float* wq = (const float*)d_in[4];
    const float* bq = (const float*)d_in[5];
    const float* wk = (const float*)d_in[6];
    const float* bk = (const float*)d_in[7];
    const float* wv = (const float*)d_in[8];
    const float* bv = (const float*)d_in[9];
    const float* wy = (const float*)d_in[10];
    const float* by = (const float*)d_in[11];

    const size_t elems = (size_t)BB * HH * SS * DD;   // 4,194,304
    float* qb  = (float*)d_ws;
    float* kb  = qb + elems;
    float* vb  = kb + elems;
    float* avb = vb + elems;

    dim3 ggrid(MROWS / 64, DMODEL / 64);   // (64, 16)
    gemm_bias<<<ggrid, 256, 0, stream>>>(queries, wq, bq, qb, 1, 0);
    gemm_bias<<<ggrid, 256, 0, stream>>>(keys,    wk, bk, kb, 1, 0);
    gemm_bias<<<ggrid, 256, 0, stream>>>(values,  wv, bv, vb, 1, 0);

    attn_causal<<<dim3(16, HH, BB), 64, 0, stream>>>(qb, kb, vb, avb);

    gemm_bias<<<ggrid, 256, 0, stream>>>(avb, wy, by, (float*)d_out, 0, 1);
}

// Round 3
// 848.582 us; speedup vs baseline: 4.7506x; 4.7506x over previous
//
#include <hip/hip_runtime.h>
#include <math.h>

#define BB 2
#define SS 2048
#define HH 16
#define DD 64
#define DMODEL 1024
#define MROWS (BB * SS)   // 4096

typedef __attribute__((ext_vector_type(8))) short bf16x8;   // MFMA A/B frag: 8 bf16 (4 VGPR)
typedef __attribute__((ext_vector_type(4))) float f32x4;    // MFMA C/D frag: 4 fp32

__device__ __forceinline__ f32x4 mfma16(bf16x8 a, bf16x8 b, f32x4 c) {
    return __builtin_amdgcn_mfma_f32_16x16x32_bf16(a, b, c, 0, 0, 0);
}

// round-to-nearest-even fp32 -> bf16
__device__ __forceinline__ unsigned short bf16_1(float x) {
    unsigned u = __builtin_bit_cast(unsigned, x);
    u += 0x7fffu + ((u >> 16) & 1u);
    return (unsigned short)(u >> 16);
}
__device__ __forceinline__ unsigned pack_bf16(float a, float b) {
    unsigned ua = __builtin_bit_cast(unsigned, a);
    unsigned ub = __builtin_bit_cast(unsigned, b);
    ua += 0x7fffu + ((ua >> 16) & 1u);
    ub += 0x7fffu + ((ub >> 16) & 1u);
    return (ua >> 16) | (ub & 0xffff0000u);
}

// ---------------------------------------------------------------------------
// Convert fp32 -> bf16: [q 4M][k 4M][v 4M][wq 1M][wk 1M][wv 1M][wy 1M] = 16M elems
// ---------------------------------------------------------------------------
__global__ __launch_bounds__(256) void cvt_bf16(const float* __restrict__ q,
                                                const float* __restrict__ k,
                                                const float* __restrict__ v,
                                                const float* __restrict__ wq,
                                                const float* __restrict__ wk,
                                                const float* __restrict__ wv,
                                                const float* __restrict__ wy,
                                                unsigned short* __restrict__ dst)
{
    const size_t idx = ((size_t)blockIdx.x * 256 + threadIdx.x) * 8;
    const int mc = (int)(idx >> 20);   // 1M-element chunk id (uniform per block)
    const float* src; size_t off;
    if      (mc < 4)   { src = q;  off = idx; }
    else if (mc < 8)   { src = k;  off = idx - ((size_t)4  << 20); }
    else if (mc < 12)  { src = v;  off = idx - ((size_t)8  << 20); }
    else if (mc == 12) { src = wq; off = idx - ((size_t)12 << 20); }
    else if (mc == 13) { src = wk; off = idx - ((size_t)13 << 20); }
    else if (mc == 14) { src = wv; off = idx - ((size_t)14 << 20); }
    else               { src = wy; off = idx - ((size_t)15 << 20); }
    float4 a = *(const float4*)(src + off);
    float4 b = *(const float4*)(src + off + 4);
    uint4 o;
    o.x = pack_bf16(a.x, a.y); o.y = pack_bf16(a.z, a.w);
    o.z = pack_bf16(b.x, b.y); o.w = pack_bf16(b.z, b.w);
    *(uint4*)(dst + idx) = o;
}

// ---------------------------------------------------------------------------
// bf16 MFMA GEMM: C[m,n] = sum_k A[m,k]*W[n,k] + bias[n]
// Both A and W row-major in k (nn.Linear weight is [n][k]).
// a_mode 0: A is [m][1024].  a_mode 1: A is av (b,h,s,d): k-chunk c == head c.
// out_mode 0: bf16 (b,h,s,d).  out_mode 1: fp32 [m][1024].
// 128x128 block tile, 4 waves (2x2 of 64x64), BK=64, XOR-swizzled 16B chunks.
// ---------------------------------------------------------------------------
__global__ __launch_bounds__(256) void gemm_mfma(const unsigned short* __restrict__ A,
                                                 const unsigned short* __restrict__ W,
                                                 const float* __restrict__ bias,
                                                 void* __restrict__ out,
                                                 int a_mode, int out_mode)
{
    __shared__ int4 lds4[2048];    // A-tile [0,1024): 128 rows x 8 chunks; W-tile [1024,2048)
    const int tid = threadIdx.x;
    const int w   = tid >> 6;
    const int lane = tid & 63;
    const int L = lane & 15, Q = lane >> 4;
    const int m0 = blockIdx.x * 128;
    const int n0 = blockIdx.y * 128;
    const int wm = (w & 1) * 64;
    const int wn = (w >> 1) * 64;

    f32x4 acc[4][4] = {};   // [mt][nt]

    for (int c = 0; c < 16; ++c) {     // 16 BK=64 chunks over K=1024
        __syncthreads();
        #pragma unroll
        for (int i = 0; i < 4; ++i) {  // stage A: 1024 chunks, 4 per thread
            int cid = tid + 256 * i;
            int row = cid >> 3, ch = cid & 7;
            int m = m0 + row;
            size_t gaddr;
            if (a_mode == 0) gaddr = (size_t)m * DMODEL + (size_t)c * 64 + ch * 8;
            else {
                int b = m >> 11, s = m & 2047;
                gaddr = (((size_t)b * HH + c) * SS + s) * DD + ch * 8;
            }
            int4 val = *(const int4*)(A + gaddr);
            lds4[row * 8 + (ch ^ (row & 7))] = val;
        }
        #pragma unroll
        for (int i = 0; i < 4; ++i) {  // stage W
            int cid = tid + 256 * i;
            int row = cid >> 3, ch = cid & 7;
            int4 val = *(const int4*)(W + (size_t)(n0 + row) * DMODEL + (size_t)c * 64 + ch * 8);
            lds4[1024 + row * 8 + (ch ^ (row & 7))] = val;
        }
        __syncthreads();
        #pragma unroll
        for (int kf = 0; kf < 2; ++kf) {
            bf16x8 af[4], bfr[4];
            #pragma unroll
            for (int mt = 0; mt < 4; ++mt) {
                int row = wm + 16 * mt + L;
                af[mt] = __builtin_bit_cast(bf16x8, lds4[row * 8 + ((Q + 4 * kf) ^ (L & 7))]);
            }
            #pragma unroll
            for (int nt = 0; nt < 4; ++nt) {
                int row = wn + 16 * nt + L;
                bfr[nt] = __builtin_bit_cast(bf16x8, lds4[1024 + row * 8 + ((Q + 4 * kf) ^ (L & 7))]);
            }
            #pragma unroll
            for (int mt = 0; mt < 4; ++mt)
                #pragma unroll
                for (int nt = 0; nt < 4; ++nt)
                    acc[mt][nt] = mfma16(af[mt], bfr[nt], acc[mt][nt]);
        }
    }

    // epilogue: C row = 4Q+reg (+tile), col = L (+tile)
    #pragma unroll
    for (int mt = 0; mt < 4; ++mt)
        #pragma unroll
        for (int nt = 0; nt < 4; ++nt)
            #pragma unroll
            for (int r = 0; r < 4; ++r) {
                int m = m0 + wm + 16 * mt + 4 * Q + r;
                int n = n0 + wn + 16 * nt + L;
                float val = acc[mt][nt][r] + bias[n];
                if (out_mode == 0) {
                    int b = m >> 11, s = m & 2047, h = n >> 6, d = n & 63;
                    ((unsigned short*)out)[(((size_t)b * HH + h) * SS + s) * DD + d] = bf16_1(val);
                } else {
                    ((float*)out)[(size_t)m * DMODEL + n] = val;
                }
            }
}

// ---------------------------------------------------------------------------
// MFMA flash attention (transposed): S^T = K.Q^T, O^T = V^T.P^T, causal.
// q/k/v: bf16 (b,h,s,d). av out: bf16 (b,h,s,d).
// Block: 256 thr (4 waves), q-tile 128 (32 q/wave, 2 coltiles), KT=64.
// grid (8 pairs, H, B); pair (x, 15-x) -> uniform 36 k-tiles per block.
// LDS: Q[0,1024) 128x8 chunks | K[1024,1536) 64x8 | VT[1536,2048) 64x8 (all swizzled)
// ---------------------------------------------------------------------------
__global__ __launch_bounds__(256) void attn_mfma(const unsigned short* __restrict__ qb,
                                                 const unsigned short* __restrict__ kb,
                                                 const unsigned short* __restrict__ vb,
                                                 unsigned short* __restrict__ av)
{
    __shared__ int4 lds4[2048];
    const int tid  = threadIdx.x;
    const int w    = tid >> 6;
    const int lane = tid & 63;
    const int L = lane & 15, Q = lane >> 4;
    const int h = blockIdx.y, b = blockIdx.z;
    const size_t base = ((size_t)b * HH + h) * SS * DD;
    const float SC = 0.125f * 1.4426950408889634f;   // 1/sqrt(D) * log2(e)

    // shfl sources for P^T -> B-operand gather: src lane Q' = 2*(Q&1) (+1 for B half)
    const int srcA = L + 32 * (Q & 1);
    const int srcB = srcA + 16;

    for (int pass = 0; pass < 2; ++pass) {
        const int qt  = pass ? (15 - (int)blockIdx.x) : (int)blockIdx.x;
        const int q0  = qt * 128;
        const int q0w = q0 + 32 * w;

        __syncthreads();   // prior pass epilogue readers done
        #pragma unroll
        for (int i = 0; i < 4; ++i) {   // stage Q tile: 1024 chunks
            int cid = tid + 256 * i;
            int row = cid >> 3, ch = cid & 7;
            int4 val = *(const int4*)(qb + base + (size_t)(q0 + row) * DD + ch * 8);
            lds4[row * 8 + (ch ^ (row & 7))] = val;
        }
        __syncthreads();

        bf16x8 qf[2][2];   // [ct][kf] B-operand frags, cached whole q-tile
        #pragma unroll
        for (int ct = 0; ct < 2; ++ct)
            #pragma unroll
            for (int kf = 0; kf < 2; ++kf) {
                int row = 32 * w + 16 * ct + L;
                qf[ct][kf] = __builtin_bit_cast(bf16x8, lds4[row * 8 + ((Q + 4 * kf) ^ (L & 7))]);
            }

        float m2[2] = {-1e30f, -1e30f};   // log2-domain running max, per coltile
        float l2[2] = {0.f, 0.f};
        f32x4 acc[4][2] = {};             // O^T [d-rowtile][ct]

        const int nkt   = 2 * qt + 2;
        const int qmaxw = q0w + 31;
        for (int kt = 0; kt < nkt; ++kt) {
            const int k0 = kt * 64;
            __syncthreads();   // prev K/VT fully consumed
            #pragma unroll
            for (int i = 0; i < 2; ++i) {   // stage K rows [k0,k0+64): 512 chunks
                int cid = tid + 256 * i;
                int row = cid >> 3, ch = cid & 7;
                int4 val = *(const int4*)(kb + base + (size_t)(k0 + row) * DD + ch * 8);
                lds4[1024 + row * 8 + (ch ^ (row & 7))] = val;
            }
            {   // stage V transposed: thread does 4x4 at (k' = r4*4, d = c4*4)
                int r4 = tid >> 4, c4 = tid & 15;
                uint2 rv[4];
                #pragma unroll
                for (int i = 0; i < 4; ++i)
                    rv[i] = *(const uint2*)(vb + base + (size_t)(k0 + r4 * 4 + i) * DD + c4 * 4);
                uint2* vt2 = (uint2*)(lds4 + 1536);
                #pragma unroll
                for (int j = 0; j < 4; ++j) {
                    int vrow = c4 * 4 + j;   // d
                    unsigned e0 = ((j < 2 ? rv[0].x : rv[0].y) >> ((j & 1) * 16)) & 0xffffu;
                    unsigned e1 = ((j < 2 ? rv[1].x : rv[1].y) >> ((j & 1) * 16)) & 0xffffu;
                    unsigned e2 = ((j < 2 ? rv[2].x : rv[2].y) >> ((j & 1) * 16)) & 0xffffu;
                    unsigned e3 = ((j < 2 ? rv[3].x : rv[3].y) >> ((j & 1) * 16)) & 0xffffu;
                    uint2 wv2; wv2.x = e0 | (e1 << 16); wv2.y = e2 | (e3 << 16);
                    int ch = (r4 >> 1) ^ (vrow & 7);
                    vt2[(vrow * 8 + ch) * 2 + (r4 & 1)] = wv2;
                }
            }
            __syncthreads();

            if (k0 <= qmaxw) {   // wave-uniform work skip
                // ---- S^T = K . Q^T ----
                f32x4 st[4][2] = {};   // [k'-rowtile][ct]
                #pragma unroll
                for (int kf = 0; kf < 2; ++kf) {
                    bf16x8 kfr[4];
                    #pragma unroll
                    for (int rt = 0; rt < 4; ++rt) {
                        int row = 16 * rt + L;
                        kfr[rt] = __builtin_bit_cast(bf16x8, lds4[1024 + row * 8 + ((Q + 4 * kf) ^ (L & 7))]);
                    }
                    #pragma unroll
                    for (int rt = 0; rt < 4; ++rt)
                        #pragma unroll
                        for (int ct = 0; ct < 2; ++ct)
                            st[rt][ct] = mfma16(kfr[rt], qf[ct][kf], st[rt][ct]);
                }
                const bool need_mask = (k0 + 63 > q0w);
                // ---- online softmax (log2 domain); lane owns one q per ct ----
                unsigned pd[4][2][2];   // packed bf16 P^T: [rt][ct][{regs01,regs23}]
                #pragma unroll
                for (int ct = 0; ct < 2; ++ct) {
                    const int qg = q0w + 16 * ct + L;
                    float mx = -1e30f;
                    #pragma unroll
                    for (int rt = 0; rt < 4; ++rt)
                        #pragma unroll
                        for (int r = 0; r < 4; ++r) {
                            float s = st[rt][ct][r] * SC;
                            if (need_mask) {
                                int kg = k0 + 16 * rt + 4 * Q + r;
                                s = (kg > qg) ? -2e30f : s;
                            }
                            st[rt][ct][r] = s;
                            mx = fmaxf(mx, s);
                        }
                    mx = fmaxf(mx, __shfl_xor(mx, 16, 64));
                    mx = fmaxf(mx, __shfl_xor(mx, 32, 64));
                    float mn = fmaxf(m2[ct], mx);
                    float alpha = exp2f(m2[ct] - mn);
                    m2[ct] = mn;
                    float ls = 0.f;
                    #pragma unroll
                    for (int rt = 0; rt < 4; ++rt) {
                        #pragma unroll
                        for (int r = 0; r < 4; ++r) {
                            float p = exp2f(st[rt][ct][r] - mn);
                            st[rt][ct][r] = p;
                            ls += p;
                        }
                        pd[rt][ct][0] = pack_bf16(st[rt][ct][0], st[rt][ct][1]);
                        pd[rt][ct][1] = pack_bf16(st[rt][ct][2], st[rt][ct][3]);
                    }
                    ls += __shfl_xor(ls, 16, 64);
                    ls += __shfl_xor(ls, 32, 64);
                    l2[ct] = l2[ct] * alpha + ls;
                    #pragma unroll
                    for (int rt = 0; rt < 4; ++rt)
                        acc[rt][ct] *= alpha;
                }
                // ---- O^T += V^T . P^T ----
                // Dest lane (L,Q) needs P^T[k'=kf*32+Q*8+j][q=16ct+L], i.e. source
                // lane L+16*(2*(Q&1)+(j>>2)), rt=2kf+(Q>>1), r=j&3. rt depends on the
                // DEST lane's Q, but __shfl reads the SOURCE lane's variable -> must
                // shuffle BOTH rt candidates and select after by Q&2 (round-2 bug).
                #pragma unroll
                for (int kf = 0; kf < 2; ++kf) {
                    bf16x8 vf[4];
                    #pragma unroll
                    for (int rt = 0; rt < 4; ++rt) {
                        int row = 16 * rt + L;
                        vf[rt] = __builtin_bit_cast(bf16x8, lds4[1536 + row * 8 + ((Q + 4 * kf) ^ (L & 7))]);
                    }
                    #pragma unroll
                    for (int ct = 0; ct < 2; ++ct) {
                        unsigned lo0 = pd[2 * kf + 0][ct][0], lo1 = pd[2 * kf + 0][ct][1];
                        unsigned hi0 = pd[2 * kf + 1][ct][0], hi1 = pd[2 * kf + 1][ct][1];
                        unsigned xa_lo0 = (unsigned)__shfl((int)lo0, srcA, 64);
                        unsigned xa_lo1 = (unsigned)__shfl((int)lo1, srcA, 64);
                        unsigned xb_lo0 = (unsigned)__shfl((int)lo0, srcB, 64);
                        unsigned xb_lo1 = (unsigned)__shfl((int)lo1, srcB, 64);
                        unsigned xa_hi0 = (unsigned)__shfl((int)hi0, srcA, 64);
                        unsigned xa_hi1 = (unsigned)__shfl((int)hi1, srcA, 64);
                        unsigned xb_hi0 = (unsigned)__shfl((int)hi0, srcB, 64);
                        unsigned xb_hi1 = (unsigned)__shfl((int)hi1, srcB, 64);
                        const bool hisel = (Q & 2) != 0;
                        uint4 bw;
                        bw.x = hisel ? xa_hi0 : xa_lo0;
                        bw.y = hisel ? xa_hi1 : xa_lo1;
                        bw.z = hisel ? xb_hi0 : xb_lo0;
                        bw.w = hisel ? xb_hi1 : xb_lo1;
                        bf16x8 pf = __builtin_bit_cast(bf16x8, bw);
                        #pragma unroll
                        for (int rt = 0; rt < 4; ++rt)
                            acc[rt][ct] = mfma16(vf[rt], pf, acc[rt][ct]);
                    }
                }
            }
        }

        // ---- epilogue: normalize, transpose O^T -> O via LDS, bf16 store ----
        __syncthreads();   // all waves done reading Q/K/VT; lds4 reusable
        {
            int4* ep4 = lds4 + w * 512;   // 32 rows(q) x 16 chunks(4 fp32), swizzled
            float inv0 = 1.0f / l2[0], inv1 = 1.0f / l2[1];
            #pragma unroll
            for (int ct = 0; ct < 2; ++ct) {
                int qr = 16 * ct + L;
                float inv = ct ? inv1 : inv0;
                #pragma unroll
                for (int rt = 0; rt < 4; ++rt) {
                    f32x4 ov = acc[rt][ct] * inv;
                    ep4[qr * 16 + ((4 * rt + Q) ^ (qr & 15))] = __builtin_bit_cast(int4, ov);
                }
            }
        }
        __syncthreads();
        {
            uint2* epu = (uint2*)(lds4 + w * 512);
            #pragma unroll
            for (int i = 0; i < 16; ++i) {
                int pid = lane + 64 * i;     // fp32-pair id 0..1023
                int rr  = pid >> 5;          // local q row 0..31
                int c   = pid & 31;          // pair within row
                uint2 f2 = epu[(rr * 16 + ((c >> 1) ^ (rr & 15))) * 2 + (c & 1)];
                unsigned packed = pack_bf16(__builtin_bit_cast(float, f2.x),
                                            __builtin_bit_cast(float, f2.y));
                *(unsigned*)(av + base + (size_t)(q0 + 32 * w + rr) * DD + c * 2) = packed;
            }
        }
    }
}

extern "C" void kernel_launch(void* const* d_in, const int* in_sizes, int n_in,
                              void* d_out, int out_size, void* d_ws, size_t ws_size,
                              hipStream_t stream) {
    const float* queries = (const float*)d_in[0];
    const float* keys    = (const float*)d_in[1];
    const float* values  = (const float*)d_in[2];
    // d_in[3] = mask: exactly tril(ones) broadcast -> hardcoded causal, not read
    const float* wq = (const float*)d_in[4];
    const float* bq = (const float*)d_in[5];
    const float* wk = (const float*)d_in[6];
    const float* bk = (const float*)d_in[7];
    const float* wv = (const float*)d_in[8];
    const float* bv = (const float*)d_in[9];
    const float* wy = (const float*)d_in[10];
    const float* by = (const float*)d_in[11];

    // ws layout (bf16 elems): [qcv 4M][kcv 4M][vcv 4M][wqb 1M][wkb 1M][wvb 1M][wyb 1M]
    //                         [qh 4M][kh 4M][vh 4M][avb 4M]  = 64 MB total
    unsigned short* wsb = (unsigned short*)d_ws;
    const size_t M4 = (size_t)1 << 22, M1 = (size_t)1 << 20;
    unsigned short* qcv = wsb;
    unsigned short* kcv = qcv + M4;
    unsigned short* vcv = kcv + M4;
    unsigned short* wqb = vcv + M4;
    unsigned short* wkb = wqb + M1;
    unsigned short* wvb = wkb + M1;
    unsigned short* wyb = wvb + M1;
    unsigned short* qh  = wyb + M1;
    unsigned short* kh  = qh + M4;
    unsigned short* vh  = kh + M4;
    unsigned short* avb = vh + M4;

    cvt_bf16<<<8192, 256, 0, stream>>>(queries, keys, values, wq, wk, wv, wy, qcv);

    dim3 ggrid(MROWS / 128, DMODEL / 128);   // (32, 8)
    gemm_mfma<<<ggrid, 256, 0, stream>>>(qcv, wqb, bq, qh, 0, 0);
    gemm_mfma<<<ggrid, 256, 0, stream>>>(kcv, wkb, bk, kh, 0, 0);
    gemm_mfma<<<ggrid, 256, 0, stream>>>(vcv, wvb, bv, vh, 0, 0);

    attn_mfma<<<dim3(8, HH, BB), 256, 0, stream>>>(qh, kh, vh, avb);

    gemm_mfma<<<ggrid, 256, 0, stream>>>(avb, wyb, by, d_out, 1, 1);
}

// Round 4
// 748.601 us; speedup vs baseline: 5.3851x; 1.1336x over previous
//
#include <hip/hip_runtime.h>
#include <math.h>

#define BB 2
#define SS 2048
#define HH 16
#define DD 64
#define DMODEL 1024
#define MROWS (BB * SS)   // 4096

typedef __attribute__((ext_vector_type(8))) short bf16x8;   // MFMA A/B frag: 8 bf16 (4 VGPR)
typedef __attribute__((ext_vector_type(4))) float f32x4;    // MFMA C/D frag: 4 fp32

__device__ __forceinline__ f32x4 mfma16(bf16x8 a, bf16x8 b, f32x4 c) {
    return __builtin_amdgcn_mfma_f32_16x16x32_bf16(a, b, c, 0, 0, 0);
}

// round-to-nearest-even fp32 -> bf16
__device__ __forceinline__ unsigned short bf16_1(float x) {
    unsigned u = __builtin_bit_cast(unsigned, x);
    u += 0x7fffu + ((u >> 16) & 1u);
    return (unsigned short)(u >> 16);
}
__device__ __forceinline__ unsigned pack_bf16(float a, float b) {
    unsigned ua = __builtin_bit_cast(unsigned, a);
    unsigned ub = __builtin_bit_cast(unsigned, b);
    ua += 0x7fffu + ((ua >> 16) & 1u);
    ub += 0x7fffu + ((ub >> 16) & 1u);
    return (ua >> 16) | (ub & 0xffff0000u);
}

// ---------------------------------------------------------------------------
// Convert fp32 -> bf16: [q 4M][k 4M][v 4M][wq 1M][wk 1M][wv 1M][wy 1M] = 16M elems
// ---------------------------------------------------------------------------
__global__ __launch_bounds__(256) void cvt_bf16(const float* __restrict__ q,
                                                const float* __restrict__ k,
                                                const float* __restrict__ v,
                                                const float* __restrict__ wq,
                                                const float* __restrict__ wk,
                                                const float* __restrict__ wv,
                                                const float* __restrict__ wy,
                                                unsigned short* __restrict__ dst)
{
    const size_t idx = ((size_t)blockIdx.x * 256 + threadIdx.x) * 8;
    const int mc = (int)(idx >> 20);   // 1M-element chunk id (uniform per block)
    const float* src; size_t off;
    if      (mc < 4)   { src = q;  off = idx; }
    else if (mc < 8)   { src = k;  off = idx - ((size_t)4  << 20); }
    else if (mc < 12)  { src = v;  off = idx - ((size_t)8  << 20); }
    else if (mc == 12) { src = wq; off = idx - ((size_t)12 << 20); }
    else if (mc == 13) { src = wk; off = idx - ((size_t)13 << 20); }
    else if (mc == 14) { src = wv; off = idx - ((size_t)14 << 20); }
    else               { src = wy; off = idx - ((size_t)15 << 20); }
    float4 a = *(const float4*)(src + off);
    float4 b = *(const float4*)(src + off + 4);
    uint4 o;
    o.x = pack_bf16(a.x, a.y); o.y = pack_bf16(a.z, a.w);
    o.z = pack_bf16(b.x, b.y); o.w = pack_bf16(b.z, b.w);
    *(uint4*)(dst + idx) = o;
}

// ---------------------------------------------------------------------------
// Shared GEMM body: C[m,n] = sum_k A[m,k]*W[n,k] + bias[n], K=N=1024.
// TM=128: 4 waves as 2x2 of 64x64.  TM=64: 4 waves as 1x4 of 64x32.
// a_mode 0: A=[m][1024] bf16.  a_mode 1: A=av (b,h,s,d), k-chunk c == head.
// out_mode 0: bf16 (b,h,s,d).  out_mode 1: fp32 [m][1024].  out_mode 2: bf16 (b,h,d,s).
// ---------------------------------------------------------------------------
template<int TM>
__device__ __forceinline__ void gemm_body(const unsigned short* __restrict__ A,
                                          const unsigned short* __restrict__ W,
                                          const float* __restrict__ bias,
                                          void* __restrict__ out,
                                          int a_mode, int out_mode)
{
    constexpr int NT  = (TM == 128) ? 4 : 2;
    constexpr int ACH = TM * 8;                 // A-tile int4 chunk count
    __shared__ int4 lds4[ACH + 1024];
    const int tid = threadIdx.x;
    const int w = tid >> 6, lane = tid & 63;
    const int L = lane & 15, Q = lane >> 4;
    const int m0 = blockIdx.x * TM;
    const int n0 = blockIdx.y * 128;
    const int wm = (TM == 128) ? (w & 1) * 64 : 0;
    const int wn = (TM == 128) ? (w >> 1) * 64 : w * 32;

    f32x4 acc[4][NT] = {};

    for (int c = 0; c < 16; ++c) {     // 16 BK=64 chunks over K=1024
        __syncthreads();
        #pragma unroll
        for (int i = 0; i < TM / 32; ++i) {     // stage A tile
            int cid = tid + 256 * i;
            int row = cid >> 3, ch = cid & 7;
            int m = m0 + row;
            size_t gaddr;
            if (a_mode == 0) gaddr = (size_t)m * DMODEL + (size_t)c * 64 + ch * 8;
            else {
                int b = m >> 11, s = m & 2047;
                gaddr = (((size_t)b * HH + c) * SS + s) * DD + ch * 8;
            }
            lds4[row * 8 + (ch ^ (row & 7))] = *(const int4*)(A + gaddr);
        }
        #pragma unroll
        for (int i = 0; i < 4; ++i) {           // stage W tile (128 rows)
            int cid = tid + 256 * i;
            int row = cid >> 3, ch = cid & 7;
            lds4[ACH + row * 8 + (ch ^ (row & 7))] =
                *(const int4*)(W + (size_t)(n0 + row) * DMODEL + (size_t)c * 64 + ch * 8);
        }
        __syncthreads();
        #pragma unroll
        for (int kf = 0; kf < 2; ++kf) {
            bf16x8 af[4], bfr[NT];
            #pragma unroll
            for (int mt = 0; mt < 4; ++mt) {
                int row = wm + 16 * mt + L;
                af[mt] = __builtin_bit_cast(bf16x8, lds4[row * 8 + ((Q + 4 * kf) ^ (row & 7))]);
            }
            #pragma unroll
            for (int nt = 0; nt < NT; ++nt) {
                int row = wn + 16 * nt + L;
                bfr[nt] = __builtin_bit_cast(bf16x8, lds4[ACH + row * 8 + ((Q + 4 * kf) ^ (row & 7))]);
            }
            #pragma unroll
            for (int mt = 0; mt < 4; ++mt)
                #pragma unroll
                for (int nt = 0; nt < NT; ++nt)
                    acc[mt][nt] = mfma16(af[mt], bfr[nt], acc[mt][nt]);
        }
    }

    // epilogue: C row = wm+16mt+4Q+r, col = wn+16nt+L
    #pragma unroll
    for (int mt = 0; mt < 4; ++mt)
        #pragma unroll
        for (int nt = 0; nt < NT; ++nt) {
            const int mbase = m0 + wm + 16 * mt + 4 * Q;
            const int n = n0 + wn + 16 * nt + L;
            float v0 = acc[mt][nt][0] + bias[n];
            float v1 = acc[mt][nt][1] + bias[n];
            float v2 = acc[mt][nt][2] + bias[n];
            float v3 = acc[mt][nt][3] + bias[n];
            if (out_mode == 1) {
                float* o = (float*)out + (size_t)mbase * DMODEL + n;
                o[0] = v0; o[DMODEL] = v1; o[2 * DMODEL] = v2; o[3 * DMODEL] = v3;
            } else if (out_mode == 0) {
                int b = mbase >> 11, s = mbase & 2047, h = n >> 6, d = n & 63;
                unsigned short* o = (unsigned short*)out + (((size_t)b * HH + h) * SS + s) * DD + d;
                o[0] = bf16_1(v0); o[DD] = bf16_1(v1); o[2 * DD] = bf16_1(v2); o[3 * DD] = bf16_1(v3);
            } else {   // out_mode 2: V^T (b,h,d,s); s = mbase..mbase+3 contiguous
                int b = mbase >> 11, s = mbase & 2047, h = n >> 6, d = n & 63;
                uint2 p; p.x = pack_bf16(v0, v1); p.y = pack_bf16(v2, v3);
                *(uint2*)((unsigned short*)out + (((size_t)b * HH + h) * DD + d) * SS + s) = p;
            }
        }
}

__global__ __launch_bounds__(256) void qkv_gemm(const unsigned short* __restrict__ qcv,
                                                const unsigned short* __restrict__ kcv,
                                                const unsigned short* __restrict__ vcv,
                                                const unsigned short* __restrict__ wqb,
                                                const unsigned short* __restrict__ wkb,
                                                const unsigned short* __restrict__ wvb,
                                                const float* __restrict__ bq,
                                                const float* __restrict__ bk,
                                                const float* __restrict__ bv,
                                                unsigned short* __restrict__ qh,
                                                unsigned short* __restrict__ kh,
                                                unsigned short* __restrict__ vtb)
{
    const int z = blockIdx.z;
    const unsigned short* A = (z == 0) ? qcv : (z == 1) ? kcv : vcv;
    const unsigned short* W = (z == 0) ? wqb : (z == 1) ? wkb : wvb;
    const float* bias       = (z == 0) ? bq  : (z == 1) ? bk  : bv;
    unsigned short* out     = (z == 0) ? qh  : (z == 1) ? kh  : vtb;
    gemm_body<128>(A, W, bias, out, 0, (z == 2) ? 2 : 0);
}

__global__ __launch_bounds__(256) void out_gemm(const unsigned short* __restrict__ avb,
                                                const unsigned short* __restrict__ wyb,
                                                const float* __restrict__ by,
                                                float* __restrict__ out)
{
    gemm_body<64>(avb, wyb, by, out, 1, 1);
}

// ---------------------------------------------------------------------------
// MFMA flash attention (transposed): S^T = K.Q^T, O^T = V^T.P^T, causal.
// q,k: bf16 (b,h,s,d); vt: bf16 (b,h,d,s) pre-transposed. av out: bf16 (b,h,s,d).
// Block: 256 thr (4 waves), q-tile 64 (16 q per wave), KT=64.
// grid (16 pairs, H, B); pair (x, 31-x) -> uniform 33 k-tiles per block.
// LDS int4: Q[0,512) | K[512,1024) | VT[1024,1536), all 64 rows x 8 chunks swizzled.
// ---------------------------------------------------------------------------
__global__ __launch_bounds__(256) void attn_mfma(const unsigned short* __restrict__ qb,
                                                 const unsigned short* __restrict__ kb,
                                                 const unsigned short* __restrict__ vt,
                                                 unsigned short* __restrict__ av)
{
    __shared__ int4 lds4[1536];
    const int tid  = threadIdx.x;
    const int w    = tid >> 6;
    const int lane = tid & 63;
    const int L = lane & 15, Q = lane >> 4;
    const int h = blockIdx.y, b = blockIdx.z;
    const size_t base = ((size_t)b * HH + h) * SS * DD;   // same for (b,h,s,d) and (b,h,d,s)
    const float SC = 0.125f * 1.4426950408889634f;        // 1/sqrt(D) * log2(e)

    // P^T gather: dest lane (L,Q) pulls from src lanes L+16*(2*(Q&1)) and +16
    const int srcA = L + 32 * (Q & 1);
    const int srcB = srcA + 16;
    const bool hisel = (Q & 2) != 0;

    for (int pass = 0; pass < 2; ++pass) {
        const int qt  = pass ? (31 - (int)blockIdx.x) : (int)blockIdx.x;
        const int q0  = qt * 64;
        const int q0w = q0 + 16 * w;

        __syncthreads();   // prior pass epilogue readers done
        #pragma unroll
        for (int i = 0; i < 2; ++i) {   // stage Q tile: 512 chunks
            int cid = tid + 256 * i;
            int row = cid >> 3, ch = cid & 7;
            lds4[row * 8 + (ch ^ (row & 7))] =
                *(const int4*)(qb + base + (size_t)(q0 + row) * DD + ch * 8);
        }
        __syncthreads();

        bf16x8 qf[2];   // B-operand frags for this wave's 16 q, cached for the pass
        #pragma unroll
        for (int kf = 0; kf < 2; ++kf) {
            int row = 16 * w + L;
            qf[kf] = __builtin_bit_cast(bf16x8, lds4[row * 8 + ((Q + 4 * kf) ^ (row & 7))]);
        }

        float m2 = -1e30f, l2 = 0.f;   // log2-domain running max / denom
        f32x4 acc[4] = {};             // O^T rows d=16rt+4Q+r, col q=16w+L

        const int nkt = qt + 1;
        for (int kt = 0; kt < nkt; ++kt) {
            const int k0 = kt * 64;
            __syncthreads();   // prev K/VT fully consumed
            #pragma unroll
            for (int i = 0; i < 2; ++i) {   // stage K: 512 chunks
                int cid = tid + 256 * i;
                int row = cid >> 3, ch = cid & 7;
                lds4[512 + row * 8 + (ch ^ (row & 7))] =
                    *(const int4*)(kb + base + (size_t)(k0 + row) * DD + ch * 8);
            }
            #pragma unroll
            for (int i = 0; i < 2; ++i) {   // stage V^T: 512 chunks (rows = d)
                int cid = tid + 256 * i;
                int row = cid >> 3, ch = cid & 7;
                lds4[1024 + row * 8 + (ch ^ (row & 7))] =
                    *(const int4*)(vt + base + (size_t)row * SS + k0 + ch * 8);
            }
            __syncthreads();

            // ---- S^T = K . Q^T ----
            f32x4 st[4] = {};   // rows k'=16rt+4Q+r, col q=16w+L
            #pragma unroll
            for (int kf = 0; kf < 2; ++kf) {
                bf16x8 kfr[4];
                #pragma unroll
                for (int rt = 0; rt < 4; ++rt) {
                    int row = 16 * rt + L;
                    kfr[rt] = __builtin_bit_cast(bf16x8, lds4[512 + row * 8 + ((Q + 4 * kf) ^ (row & 7))]);
                }
                #pragma unroll
                for (int rt = 0; rt < 4; ++rt)
                    st[rt] = mfma16(kfr[rt], qf[kf], st[rt]);
            }

            // ---- online softmax (log2 domain) ----
            const bool need_mask = (k0 + 63 > q0w);   // only the diagonal tile
            const int qg = q0w + L;
            float mx = -1e30f;
            #pragma unroll
            for (int rt = 0; rt < 4; ++rt)
                #pragma unroll
                for (int r = 0; r < 4; ++r) {
                    float s = st[rt][r] * SC;
                    if (need_mask) {
                        int kg = k0 + 16 * rt + 4 * Q + r;
                        s = (kg > qg) ? -2e30f : s;
                    }
                    st[rt][r] = s;
                    mx = fmaxf(mx, s);
                }
            mx = fmaxf(mx, __shfl_xor(mx, 16, 64));
            mx = fmaxf(mx, __shfl_xor(mx, 32, 64));
            const float mn = fmaxf(m2, mx);
            const float alpha = exp2f(m2 - mn);
            m2 = mn;
            float ls = 0.f;
            unsigned pd[4][2];   // packed bf16 P^T
            #pragma unroll
            for (int rt = 0; rt < 4; ++rt) {
                float p0 = exp2f(st[rt][0] - mn), p1 = exp2f(st[rt][1] - mn);
                float p2 = exp2f(st[rt][2] - mn), p3 = exp2f(st[rt][3] - mn);
                ls += (p0 + p1) + (p2 + p3);
                pd[rt][0] = pack_bf16(p0, p1);
                pd[rt][1] = pack_bf16(p2, p3);
            }
            ls += __shfl_xor(ls, 16, 64);
            ls += __shfl_xor(ls, 32, 64);
            l2 = l2 * alpha + ls;
            #pragma unroll
            for (int rt = 0; rt < 4; ++rt) acc[rt] *= alpha;

            // ---- O^T += V^T . P^T  (shuffle both rt candidates, select by Q&2) ----
            #pragma unroll
            for (int kf = 0; kf < 2; ++kf) {
                bf16x8 vf[4];
                #pragma unroll
                for (int rt = 0; rt < 4; ++rt) {
                    int row = 16 * rt + L;
                    vf[rt] = __builtin_bit_cast(bf16x8, lds4[1024 + row * 8 + ((Q + 4 * kf) ^ (row & 7))]);
                }
                unsigned lo0 = pd[2 * kf + 0][0], lo1 = pd[2 * kf + 0][1];
                unsigned hi0 = pd[2 * kf + 1][0], hi1 = pd[2 * kf + 1][1];
                unsigned xa_lo0 = (unsigned)__shfl((int)lo0, srcA, 64);
                unsigned xa_lo1 = (unsigned)__shfl((int)lo1, srcA, 64);
                unsigned xb_lo0 = (unsigned)__shfl((int)lo0, srcB, 64);
                unsigned xb_lo1 = (unsigned)__shfl((int)lo1, srcB, 64);
                unsigned xa_hi0 = (unsigned)__shfl((int)hi0, srcA, 64);
                unsigned xa_hi1 = (unsigned)__shfl((int)hi1, srcA, 64);
                unsigned xb_hi0 = (unsigned)__shfl((int)hi0, srcB, 64);
                unsigned xb_hi1 = (unsigned)__shfl((int)hi1, srcB, 64);
                uint4 bw;
                bw.x = hisel ? xa_hi0 : xa_lo0;
                bw.y = hisel ? xa_hi1 : xa_lo1;
                bw.z = hisel ? xb_hi0 : xb_lo0;
                bw.w = hisel ? xb_hi1 : xb_lo1;
                bf16x8 pf = __builtin_bit_cast(bf16x8, bw);
                #pragma unroll
                for (int rt = 0; rt < 4; ++rt)
                    acc[rt] = mfma16(vf[rt], pf, acc[rt]);
            }
        }

        // ---- epilogue: normalize, transpose O^T -> O via LDS, bf16 store ----
        __syncthreads();   // all waves done reading Q/K/VT
        {
            int4* ep4 = lds4 + w * 256;   // 16 rows(q=L) x 16 chunks(f32x4 over d)
            const float inv = 1.0f / l2;
            #pragma unroll
            for (int rt = 0; rt < 4; ++rt) {
                f32x4 ov = acc[rt] * inv;
                ep4[L * 16 + ((4 * rt + Q) ^ (L & 15))] = __builtin_bit_cast(int4, ov);
            }
        }
        __syncthreads();
        {
            uint2* epu = (uint2*)(lds4 + w * 256);
            #pragma unroll
            for (int i = 0; i < 8; ++i) {
                int pid = lane + 64 * i;     // f32-pair id 0..511
                int rr  = pid >> 5;          // local q row 0..15
                int c   = pid & 31;          // pair within row
                uint2 f2 = epu[(rr * 16 + ((c >> 1) ^ (rr & 15))) * 2 + (c & 1)];
                unsigned packed = pack_bf16(__builtin_bit_cast(float, f2.x),
                                            __builtin_bit_cast(float, f2.y));
                *(unsigned*)(av + base + (size_t)(q0 + 16 * w + rr) * DD + c * 2) = packed;
            }
        }
    }
}

extern "C" void kernel_launch(void* const* d_in, const int* in_sizes, int n_in,
                              void* d_out, int out_size, void* d_ws, size_t ws_size,
                              hipStream_t stream) {
    const float* queries = (const float*)d_in[0];
    const float* keys    = (const float*)d_in[1];
    const float* values  = (const float*)d_in[2];
    // d_in[3] = mask: exactly tril(ones) broadcast -> hardcoded causal, not read
    const float* wq = (const float*)d_in[4];
    const float* bq = (const float*)d_in[5];
    const float* wk = (const float*)d_in[6];
    const float* bk = (const float*)d_in[7];
    const float* wv = (const float*)d_in[8];
    const float* bv = (const float*)d_in[9];
    const float* wy = (const float*)d_in[10];
    const float* by = (const float*)d_in[11];

    // ws layout (bf16 elems): [qcv 4M][kcv 4M][vcv 4M][wqb 1M][wkb 1M][wvb 1M][wyb 1M]
    //                         [qh 4M][kh 4M][vtb 4M][avb 4M]  = 64 MB total
    unsigned short* wsb = (unsigned short*)d_ws;
    const size_t M4 = (size_t)1 << 22, M1 = (size_t)1 << 20;
    unsigned short* qcv = wsb;
    unsigned short* kcv = qcv + M4;
    unsigned short* vcv = kcv + M4;
    unsigned short* wqb = vcv + M4;
    unsigned short* wkb = wqb + M1;
    unsigned short* wvb = wkb + M1;
    unsigned short* wyb = wvb + M1;
    unsigned short* qh  = wyb + M1;
    unsigned short* kh  = qh + M4;
    unsigned short* vtb = kh + M4;
    unsigned short* avb = vtb + M4;

    cvt_bf16<<<8192, 256, 0, stream>>>(queries, keys, values, wq, wk, wv, wy, qcv);

    qkv_gemm<<<dim3(MROWS / 128, DMODEL / 128, 3), 256, 0, stream>>>(
        qcv, kcv, vcv, wqb, wkb, wvb, bq, bk, bv, qh, kh, vtb);

    attn_mfma<<<dim3(16, HH, BB), 256, 0, stream>>>(qh, kh, vtb, avb);

    out_gemm<<<dim3(MROWS / 64, DMODEL / 128), 256, 0, stream>>>(avb, wyb, by, (float*)d_out);
}